// Round 5
// baseline (1082.938 us; speedup 1.0000x reference)
//
#include <hip/hip_runtime.h>
#include <cstdint>
#include <cstddef>

typedef float  f32x4 __attribute__((ext_vector_type(4)));
typedef short  s16x8 __attribute__((ext_vector_type(8)));
typedef unsigned short u16;
typedef unsigned int   u32;
typedef u32 u32x4 __attribute__((ext_vector_type(4)));
typedef u32 u32x2 __attribute__((ext_vector_type(2)));

#define TOPK 7

__device__ __forceinline__ u16 f2bf(float f) {
  u32 u = __float_as_uint(f);
  u32 r = (u + 0x7FFFu + ((u >> 16) & 1u)) >> 16;   // RNE
  return (u16)r;
}
__device__ __forceinline__ float b2f(u16 s) {
  return __uint_as_float(((u32)s) << 16);
}

typedef __attribute__((address_space(1))) void gvoid;
typedef __attribute__((address_space(3))) void lvoid;
__device__ __forceinline__ void gl_lds16(const void* g, void* l) {
  __builtin_amdgcn_global_load_lds((gvoid*)g, (lvoid*)l, 16, 0, 0);
}

// ---------------- fp32 -> bf16 convert (for weight matrices) ----------------
__global__ void cvt_kernel(const float* __restrict__ src, u16* __restrict__ dst, int n8) {
  int i = blockIdx.x * 256 + threadIdx.x;
  if (i >= n8) return;
  const f32x4* sp = (const f32x4*)src + (size_t)i * 2;
  f32x4 a = sp[0], b = sp[1];
  alignas(16) u16 o[8];
#pragma unroll
  for (int j = 0; j < 4; ++j) { o[j] = f2bf(a[j]); o[4 + j] = f2bf(b[j]); }
  *(u32x4*)(dst + (size_t)i * 8) = *(u32x4*)o;
}

// ---------------- bf16 MFMA GEMM, C = A @ B^T  (A[M,K], B[N,K]) -------------
// MODE 0: A fp32 (activations), write bf16 TRANSPOSED out[b][n][l]  (m = b*2048 + l)
// MODE 1: A bf16, write fp32 out[m][n] + bias[n]
template<int MODE>
__global__ __launch_bounds__(256, 2) void gemm_bt(
    const void* __restrict__ Aptr, const u16* __restrict__ Bw,
    void* __restrict__ Cout, const float* __restrict__ bias)
{
  constexpr int K = 1024, N = 1024;
  __shared__ __align__(16) u16 lA[128 * 32];
  __shared__ __align__(16) u16 lB[128 * 32];

  int bx = blockIdx.x;
  int wg = (bx & 7) * 256 + (bx >> 3);        // XCD swizzle (nwg=2048, 8 | nwg)
  int tm = wg >> 3, tn = wg & 7;
  int m0 = tm * 128, n0 = tn * 128;

  int t = threadIdx.x;
  int wid = t >> 6, lane = t & 63;
  int wm = wid >> 1, wn = wid & 1;
  int lr = lane & 15, kb = lane >> 4;

  f32x4 acc[4][4] = {};

  for (int kt = 0; kt < 32; ++kt) {
    int k0 = kt * 32;
    // ---- stage A tile [128][32] ----
    if constexpr (MODE == 0) {
      const float* A = (const float*)Aptr;
      int r = t >> 1, half = t & 1;
      const float* ap = A + (size_t)(m0 + r) * K + k0 + half * 16;
      f32x4 v[4];
#pragma unroll
      for (int g = 0; g < 4; ++g) v[g] = ((const f32x4*)ap)[g];
      alignas(16) u16 o[16];
#pragma unroll
      for (int j = 0; j < 16; ++j) o[j] = f2bf(v[j >> 2][j & 3]);
      *(u32x4*)&lA[r * 32 + half * 16]     = *(u32x4*)&o[0];
      *(u32x4*)&lA[r * 32 + half * 16 + 8] = *(u32x4*)&o[8];
    } else {
      const u16* A = (const u16*)Aptr;
#pragma unroll
      for (int it = 0; it < 2; ++it) {
        int o = t * 16 + it * 4096;          // byte offset in LDS tile
        int e = o >> 1;
        int row = e >> 5, col = e & 31;
        gl_lds16(A + (size_t)(m0 + row) * K + k0 + col,
                 (char*)lA + wid * 1024 + it * 4096);
      }
    }
    // ---- stage B tile [128][32] via global_load_lds ----
#pragma unroll
    for (int it = 0; it < 2; ++it) {
      int o = t * 16 + it * 4096;
      int e = o >> 1;
      int row = e >> 5, col = e & 31;
      gl_lds16(Bw + (size_t)(n0 + row) * K + k0 + col,
               (char*)lB + wid * 1024 + it * 4096);
    }
    __syncthreads();

    s16x8 af[4], bf[4];
#pragma unroll
    for (int mi = 0; mi < 4; ++mi)
      af[mi] = *(const s16x8*)&lA[(wm * 64 + mi * 16 + lr) * 32 + kb * 8];
#pragma unroll
    for (int ni = 0; ni < 4; ++ni)
      bf[ni] = *(const s16x8*)&lB[(wn * 64 + ni * 16 + lr) * 32 + kb * 8];
#pragma unroll
    for (int mi = 0; mi < 4; ++mi)
#pragma unroll
      for (int ni = 0; ni < 4; ++ni)
        acc[mi][ni] = __builtin_amdgcn_mfma_f32_16x16x32_bf16(af[mi], bf[ni], acc[mi][ni], 0, 0, 0);
    __syncthreads();
  }

  // ---- epilogue ----
#pragma unroll
  for (int mi = 0; mi < 4; ++mi) {
    int mbase = m0 + wm * 64 + mi * 16 + kb * 4;   // C row = (lane>>4)*4 + reg
#pragma unroll
    for (int ni = 0; ni < 4; ++ni) {
      int nn = n0 + wn * 64 + ni * 16 + lr;        // C col = lane&15
      if constexpr (MODE == 0) {
        u16* OT = (u16*)Cout;
        int b = mbase >> 11, l = mbase & 2047;     // 4 consecutive l, same b
        alignas(8) u16 pk[4];
#pragma unroll
        for (int j = 0; j < 4; ++j) pk[j] = f2bf(acc[mi][ni][j]);
        *(u32x2*)(OT + ((size_t)((b << 10) + nn)) * 2048 + l) = *(u32x2*)pk;
      } else {
        float* C = (float*)Cout;
        float bv = bias[nn];
#pragma unroll
        for (int j = 0; j < 4; ++j)
          C[(size_t)(mbase + j) * N + nn] = acc[mi][ni][j] + bv;
      }
    }
  }
}

// ======================= FFT-based circular correlation =====================
// corr[row] = irfft( rfft(Q[row]) * conj(rfft(K[row])) ), L=2048.
// Packed half-size complex FFT: z[n] = x[2n] + i*x[2n+1], M=1024.
// Four-step 32x32 FFT, 32 threads/row, 8 rows per 256-thread block.

__device__ __constant__ const int BRv[32] = {
  0,16,8,24,4,20,12,28,2,18,10,26,6,22,14,30,
  1,17,9,25,5,21,13,29,3,19,11,27,7,23,15,31};
__device__ const float C32v[16] = {
  1.0f, 0.98078528f, 0.92387953f, 0.83146961f,
  0.70710678f, 0.55557023f, 0.38268343f, 0.19509032f,
  0.0f, -0.19509032f, -0.38268343f, -0.55557023f,
  -0.70710678f, -0.83146961f, -0.92387953f, -0.98078528f};
__device__ const float S32v[16] = {
  0.0f, 0.19509032f, 0.38268343f, 0.55557023f,
  0.70710678f, 0.83146961f, 0.92387953f, 0.98078528f,
  1.0f, 0.98078528f, 0.92387953f, 0.83146961f,
  0.70710678f, 0.55557023f, 0.38268343f, 0.19509032f};

#define TWIDX(j) ((j) + ((j) >> 4))

// in-place 32-pt DIT DFT; input must be bit-reversed, output natural order.
template<bool INV>
__device__ __forceinline__ void dft32(float* xr, float* xi) {
#pragma unroll
  for (int s = 0; s < 5; ++s) {
    const int half = 1 << s, step = 16 >> s;
#pragma unroll
    for (int blk = 0; blk < 32; blk += 2 * half) {
#pragma unroll
      for (int j = 0; j < half; ++j) {
        float wr = C32v[j * step];
        float wi = INV ? S32v[j * step] : -S32v[j * step];
        int p = blk + j, q = p + half;
        float vr = xr[q] * wr - xi[q] * wi;
        float vi = xr[q] * wi + xi[q] * wr;
        xr[q] = xr[p] - vr; xi[q] = xi[p] - vi;
        xr[p] = xr[p] + vr; xi[p] = xi[p] + vi;
      }
    }
  }
}

__device__ __forceinline__ float bperm(int addr, float v) {
  return __int_as_float(__builtin_amdgcn_ds_bpermute(addr, __float_as_int(v)));
}

// forward 1024-pt complex FFT of packed row (bf16 pairs as u32), four-step.
// result: thread tt holds Z[tt + 32*k2] in (xr[k2], xi[k2]).
__device__ __forceinline__ void fft_fwd_row(const u32* __restrict__ zrow, int tt,
                                            float2* wsr, const float2* tw,
                                            float* xr, float* xi) {
#pragma unroll
  for (int i = 0; i < 32; ++i) {
    u32 v = zrow[32 * BRv[i] + tt];
    xr[i] = b2f((u16)(v & 0xffffu));
    xi[i] = b2f((u16)(v >> 16));
  }
  dft32<false>(xr, xi);
#pragma unroll
  for (int k1 = 0; k1 < 32; ++k1) {
    float2 w = tw[TWIDX(tt * k1)];               // e^{-2pi i * tt*k1/1024}
    float2 o;
    o.x = xr[k1] * w.x - xi[k1] * w.y;
    o.y = xr[k1] * w.y + xi[k1] * w.x;
    wsr[k1 * 33 + tt] = o;
  }
  __syncthreads();
#pragma unroll
  for (int i = 0; i < 32; ++i) {
    float2 v = wsr[tt * 33 + BRv[i]];
    xr[i] = v.x; xi[i] = v.y;
  }
  __syncthreads();
  dft32<false>(xr, xi);
}

// one spectral bin: Zl/Zp are Z[k], Z[M-k] (pre-conj) for Q and K; W = e^{-i pi k/M}.
// out = Zc[k] * (1/1024), with all 0.5 factors folded (total 1/8192 on unscaled G's).
__device__ __forceinline__ void spec_bin(
    float zlQr, float zlQi, float zpQr, float zpQi,
    float zlKr, float zlKi, float zpKr, float zpKi,
    float wr, float wi, float& outr, float& outi)
{
  // A2 = Zl + conj(Zp), B2 = Zl - conj(Zp); G = A2 - i*W*B2 (=2*X[k])
  float aQr = zlQr + zpQr, aQi = zlQi - zpQi;
  float bQr = zlQr - zpQr, bQi = zlQi + zpQi;
  float gQr  = aQr + wr * bQi + wi * bQr;
  float gQi  = aQi - (wr * bQr - wi * bQi);
  float gQpr = aQr - wr * bQi - wi * bQr;       // 2*X[M-k]
  float gQpi = -aQi - wr * bQr + wi * bQi;
  float aKr = zlKr + zpKr, aKi = zlKi - zpKi;
  float bKr = zlKr - zpKr, bKi = zlKi + zpKi;
  float gKr  = aKr + wr * bKi + wi * bKr;
  float gKi  = aKi - (wr * bKr - wi * bKi);
  float gKpr = aKr - wr * bKi - wi * bKr;
  float gKpi = -aKi - wr * bKr + wi * bKi;
  // Ct = Gq*conj(Gk) (=4*C[k]); CPt = Gq'*conj(Gk') (=4*C[M-k])
  float ctr = gQr * gKr + gQi * gKi;
  float cti = gQi * gKr - gQr * gKi;
  float cpr = gQpr * gKpr + gQpi * gKpi;
  float cpi = gQpi * gKpr - gQpr * gKpi;
  // Zc = 0.5*(Ut + i*conj(W)*Vt)/4 /1024  => *(1/8192)
  float utr = ctr + cpr, uti = cti - cpi;
  float vtr = ctr - cpr, vti = cti + cpi;
  outr = (utr - wr * vti + wi * vtr) * (1.0f / 8192.0f);
  outi = (uti + wr * vtr + wi * vti) * (1.0f / 8192.0f);
}

__global__ __launch_bounds__(256) __attribute__((amdgpu_waves_per_eu(2, 2)))
void fftcorr_kernel(
    const u16* __restrict__ Qt, const u16* __restrict__ Kt, float* __restrict__ corr)
{
  __shared__ float2 tw[1088];        // e^{-2pi i j/1024}, padded idx j+(j>>4)
  __shared__ float2 wsb[8][1056];    // per-row 32x33 exchange buffer

  int t = threadIdx.x;
#pragma unroll
  for (int i = 0; i < 4; ++i) {
    int j = t + 256 * i;
    float s, c;
    __sincosf((float)j * -6.135923151e-3f, &s, &c);   // -2*pi/1024
    float2 w; w.x = c; w.y = s;
    tw[TWIDX(j)] = w;
  }
  __syncthreads();

  int rl = t >> 5, tt = t & 31;
  int row = blockIdx.x * 8 + rl;
  const u32* qrow = (const u32*)Qt + (size_t)row * 1024;
  const u32* krow = (const u32*)Kt + (size_t)row * 1024;
  float2* wsr = wsb[rl];
  int lw = t & 63;
  int paddr = (((-tt) & 31) | (lw & 32)) << 2;   // partner lane (M-k pairing)
  bool f0 = (tt == 0);

  float zkr[32], zki[32], ar[32], ai[32], zcr[32], zci[32];

  fft_fwd_row(krow, tt, wsr, tw, zkr, zki);
  fft_fwd_row(qrow, tt, wsr, tw, ar, ai);

  // spectral: C = Xq * conj(Xk), repack to packed inverse spectrum Zc
#pragma unroll
  for (int j = 0; j < 16; ++j) {
    // bin A: k = tt + 32*j (local reg j); bin B: k = tt + 32*(31-j) (reg 31-j)
    float qpAr = bperm(paddr, ar[31 - j]),  qpAi = bperm(paddr, ai[31 - j]);
    float kpAr = bperm(paddr, zkr[31 - j]), kpAi = bperm(paddr, zki[31 - j]);
    float qpBr = bperm(paddr, ar[j]),       qpBi = bperm(paddr, ai[j]);
    float kpBr = bperm(paddr, zkr[j]),      kpBi = bperm(paddr, zki[j]);
    if (f0) {  // lane 0: partner is itself with k2-wrap instead of lane-wrap
      qpAr = ar[(32 - j) & 31];  qpAi = ai[(32 - j) & 31];
      kpAr = zkr[(32 - j) & 31]; kpAi = zki[(32 - j) & 31];
      qpBr = ar[(j + 1) & 31];   qpBi = ai[(j + 1) & 31];
      kpBr = zkr[(j + 1) & 31];  kpBi = zki[(j + 1) & 31];
    }
    // W = e^{-i pi k/1024}: tw[k>>1] (* e^{-i pi/1024} if k odd; odd iff tt odd)
    float2 bA = tw[TWIDX((tt >> 1) + 16 * j)];
    float2 bB = tw[TWIDX((tt >> 1) + 16 * (31 - j))];
    bool oddk = (tt & 1);
    float mr = oddk ? 0.999995293810f : 1.0f;
    float mi = oddk ? -3.067956763e-3f : 0.0f;
    float wAr = bA.x * mr - bA.y * mi, wAi = bA.x * mi + bA.y * mr;
    float wBr = bB.x * mr - bB.y * mi, wBi = bB.x * mi + bB.y * mr;
    spec_bin(ar[j], ai[j], qpAr, qpAi, zkr[j], zki[j], kpAr, kpAi,
             wAr, wAi, zcr[j], zci[j]);
    spec_bin(ar[31 - j], ai[31 - j], qpBr, qpBi, zkr[31 - j], zki[31 - j],
             kpBr, kpBi, wBr, wBi, zcr[31 - j], zci[31 - j]);
  }

  // inverse 1024-pt FFT of Zc (unscaled; 1/1024 already folded above)
#define SWP(a, b) { float t1 = zcr[a]; zcr[a] = zcr[b]; zcr[b] = t1; \
                    float t2 = zci[a]; zci[a] = zci[b]; zci[b] = t2; }
  SWP(1, 16) SWP(2, 8) SWP(3, 24) SWP(5, 20) SWP(6, 12) SWP(7, 28)
  SWP(9, 18) SWP(11, 26) SWP(13, 22) SWP(15, 30) SWP(19, 25) SWP(23, 29)
#undef SWP
  dft32<true>(zcr, zci);
#pragma unroll
  for (int v1 = 0; v1 < 32; ++v1) {
    float2 w = tw[TWIDX(tt * v1)];               // conj -> e^{+2pi i tt*v1/1024}
    float2 o;
    o.x = zcr[v1] * w.x + zci[v1] * w.y;
    o.y = zci[v1] * w.x - zcr[v1] * w.y;
    wsr[v1 * 33 + tt] = o;
  }
  __syncthreads();
#pragma unroll
  for (int i = 0; i < 32; ++i) {
    float2 v = wsr[tt * 33 + BRv[i]];
    zcr[i] = v.x; zci[i] = v.y;
  }
  dft32<true>(zcr, zci);

  // zc[n]: thread tt holds n = tt + 32*v2 -> corr[2n]=Re, corr[2n+1]=Im
  float2* crow = (float2*)(corr + (size_t)row * 2048);
#pragma unroll
  for (int v2 = 0; v2 < 32; ++v2) {
    float2 o; o.x = zcr[v2]; o.y = zci[v2];
    crow[tt + 32 * v2] = o;
  }
}

// ---------------- mean over heads: corr[b][h*64+d][l] -> mean[b][d][l] ------
__global__ void mean_kernel(const float* __restrict__ corr, float* __restrict__ meanp) {
  int idx = blockIdx.x * 256 + threadIdx.x;   // 524288 float4 groups
  int l4 = idx & 511;
  int d  = (idx >> 9) & 63;
  int b  = idx >> 15;
  const f32x4* cp = (const f32x4*)corr;
  f32x4 s = {};
#pragma unroll
  for (int h = 0; h < 16; ++h)
    s += cp[((size_t)(b * 1024 + h * 64 + d)) * 512 + l4];
  ((f32x4*)meanp)[(size_t)(b * 64 + d) * 512 + l4] = s * 0.0625f;
}

// ---------------- top-7 + softmax per (b,d) row -----------------------------
__global__ __launch_bounds__(256) void topk_kernel(
    const float* __restrict__ meanp, int* __restrict__ delays, float* __restrict__ wts)
{
  int row = blockIdx.x;                        // b*64 + d  (consumed as h*64 + d)
  const float* mr = meanp + (size_t)row * 2048;
  int t = threadIdx.x;
  float v[8];
#pragma unroll
  for (int j = 0; j < 8; ++j) v[j] = mr[t * 8 + j];
  __shared__ float sV[256];
  __shared__ int   sI[256];
  __shared__ float topv[TOPK];
  __shared__ int   topi[TOPK];
  for (int rnd = 0; rnd < TOPK; ++rnd) {
    float bv = v[0]; int bi = t * 8;
#pragma unroll
    for (int j = 1; j < 8; ++j)
      if (v[j] > bv) { bv = v[j]; bi = t * 8 + j; }   // strict > : ties keep lowest idx
    sV[t] = bv; sI[t] = bi;
    __syncthreads();
    for (int off = 128; off > 0; off >>= 1) {
      if (t < off) {
        float ov = sV[t + off]; int oi = sI[t + off];
        if (ov > sV[t] || (ov == sV[t] && oi < sI[t])) { sV[t] = ov; sI[t] = oi; }
      }
      __syncthreads();
    }
    int wi = sI[0];
    if (t == 0) { topv[rnd] = sV[0]; topi[rnd] = wi; }
    if ((wi >> 3) == t) {
#pragma unroll
      for (int j = 0; j < 8; ++j)                    // static idx (no scratch)
        if ((wi & 7) == j) v[j] = -__builtin_inff();
    }
    __syncthreads();
  }
  if (t == 0) {
    float mx = topv[0], sum = 0.f, e[TOPK];
#pragma unroll
    for (int i = 0; i < TOPK; ++i) { e[i] = expf(topv[i] - mx); sum += e[i]; }
#pragma unroll
    for (int i = 0; i < TOPK; ++i) {
      wts[row * 8 + i]    = e[i] / sum;
      delays[row * 8 + i] = topi[i];
    }
  }
}

// ---------------- delay-roll aggregation: aggt[b][c][l] ---------------------
__global__ __launch_bounds__(256) void agg_kernel(
    const u16* __restrict__ Vt, const float* __restrict__ wts,
    const int* __restrict__ delays, u16* __restrict__ aggt)
{
  int row = blockIdx.x;           // b*1024 + c
  int c = row & 1023;             // weights index: (c>>6)*64 + (c&63) == c
  __shared__ __align__(16) float Vs[4608];
  __shared__ float wsh[TOPK];
  __shared__ int   dsh[TOPK];
  int t = threadIdx.x;
  if (t < TOPK) { wsh[t] = wts[c * 8 + t]; dsh[t] = delays[c * 8 + t]; }
  const u16* vr = Vt + (size_t)row * 2048;
  u32x4 rv = *(const u32x4*)(vr + t * 8);
  alignas(16) u16 uv[8];
  *(u32x4*)uv = rv;
  int f0 = t * 8;
#pragma unroll
  for (int j = 0; j < 8; ++j) {
    float fv = b2f(uv[j]);
    int f  = f0 + j;
    int f2 = f + 2048;
    Vs[f  + ((f  >> 5) << 2)] = fv;
    Vs[f2 + ((f2 >> 5) << 2)] = fv;
  }
  __syncthreads();
  float o[8] = {0, 0, 0, 0, 0, 0, 0, 0};
#pragma unroll
  for (int i = 0; i < TOPK; ++i) {
    float w = wsh[i]; int dl = dsh[i];
    int base = f0 + dl;
#pragma unroll
    for (int j = 0; j < 8; ++j) {
      int f = base + j;                       // <= 4094, dup covers mod L
      o[j] += w * Vs[f + ((f >> 5) << 2)];
    }
  }
  alignas(16) u16 ob[8];
#pragma unroll
  for (int j = 0; j < 8; ++j) ob[j] = f2bf(o[j]);
  *(u32x4*)(aggt + (size_t)row * 2048 + f0) = *(u32x4*)ob;
}

// ---------------- transpose aggt[b][c][l] -> aggb[b][l][c] (bf16) -----------
__global__ __launch_bounds__(256) void transpose_kernel(
    const u16* __restrict__ aggt, u16* __restrict__ aggb)
{
  int bid = blockIdx.x;
  int lt = bid & 31;
  int ct = (bid >> 5) & 15;
  int b  = bid >> 9;
  __shared__ __align__(16) u16 tile[64][72];
  int t = threadIdx.x;
  int r = t >> 2, seg = t & 3;
  const u16* src = aggt + ((size_t)(b * 1024 + ct * 64 + r)) * 2048 + lt * 64 + seg * 16;
  u32x4 v0 = *(const u32x4*)src;
  u32x4 v1 = *(const u32x4*)(src + 8);
  *(u32x4*)&tile[r][seg * 16]     = v0;
  *(u32x4*)&tile[r][seg * 16 + 8] = v1;
  __syncthreads();
  alignas(16) u16 tmp[16];
#pragma unroll
  for (int j = 0; j < 16; ++j) tmp[j] = tile[seg * 16 + j][r];
  u16* dst = aggb + ((size_t)(b * 2048 + lt * 64 + r)) * 1024 + ct * 64 + seg * 16;
  *(u32x4*)dst       = *(u32x4*)&tmp[0];
  *(u32x4*)(dst + 8) = *(u32x4*)&tmp[8];
}

// ---------------------------------------------------------------------------
extern "C" void kernel_launch(void* const* d_in, const int* in_sizes, int n_in,
                              void* d_out, int out_size, void* d_ws, size_t ws_size,
                              hipStream_t stream) {
  (void)in_sizes; (void)n_in; (void)out_size; (void)ws_size;
  const float* qin = (const float*)d_in[0];
  const float* kin = (const float*)d_in[1];
  const float* vin = (const float*)d_in[2];
  const float* Wq  = (const float*)d_in[3];
  const float* Wk  = (const float*)d_in[4];
  const float* Wv  = (const float*)d_in[5];
  const float* Wo  = (const float*)d_in[6];
  const float* bo  = (const float*)d_in[7];

  float* out  = (float*)d_out;                  // [16][2048][1024] fp32
  float* corr = out + (size_t)33554432;         // [16][1024][2048] fp32

  char* ws = (char*)d_ws;
  u16* Qt  = (u16*)ws;                                   // 64 MiB  [16][1024][2048] bf16
  u16* Kt  = (u16*)(ws + ((size_t)64  << 20));           // 64 MiB
  u16* Vt  = (u16*)(ws + ((size_t)128 << 20));           // 64 MiB
  u16* Wqb = (u16*)(ws + ((size_t)192 << 20));           // 2 MiB each
  u16* Wkb = Wqb + (1u << 20);
  u16* Wvb = Wkb + (1u << 20);
  u16* Wob = Wvb + (1u << 20);
  float* meanp  = (float*)(ws + ((size_t)200 << 20));    // 8 MiB [16][64][2048] fp32
  int*   delays = (int*)  (ws + ((size_t)208 << 20));    // [1024][8]
  float* wts    = (float*)(ws + ((size_t)208 << 20) + 65536);
  u16* aggt = Qt;   // reuse (Qt dead after corr)
  u16* aggb = Kt;   // reuse (Kt dead after corr)

  dim3 blk(256);
  cvt_kernel<<<512, blk, 0, stream>>>(Wq, Wqb, 131072);
  cvt_kernel<<<512, blk, 0, stream>>>(Wk, Wkb, 131072);
  cvt_kernel<<<512, blk, 0, stream>>>(Wv, Wvb, 131072);
  cvt_kernel<<<512, blk, 0, stream>>>(Wo, Wob, 131072);

  gemm_bt<0><<<2048, blk, 0, stream>>>(qin, Wqb, Qt, nullptr);
  gemm_bt<0><<<2048, blk, 0, stream>>>(kin, Wkb, Kt, nullptr);
  gemm_bt<0><<<2048, blk, 0, stream>>>(vin, Wvb, Vt, nullptr);

  fftcorr_kernel<<<2048, blk, 0, stream>>>(Qt, Kt, corr);
  mean_kernel<<<2048, blk, 0, stream>>>(corr, meanp);
  topk_kernel<<<1024, blk, 0, stream>>>(meanp, delays, wts);
  agg_kernel<<<16384, blk, 0, stream>>>(Vt, wts, delays, aggt);
  transpose_kernel<<<8192, blk, 0, stream>>>(aggt, aggb);
  gemm_bt<1><<<2048, blk, 0, stream>>>(aggb, Wob, out, bo);
}

// Round 6
// 826.156 us; speedup vs baseline: 1.3108x; 1.3108x over previous
//
#include <hip/hip_runtime.h>
#include <cstdint>
#include <cstddef>

typedef float  f32x4 __attribute__((ext_vector_type(4)));
typedef short  s16x8 __attribute__((ext_vector_type(8)));
typedef unsigned short u16;
typedef unsigned int   u32;
typedef u32 u32x4 __attribute__((ext_vector_type(4)));
typedef u32 u32x2 __attribute__((ext_vector_type(2)));

#define TOPK 7

__device__ __forceinline__ u16 f2bf(float f) {
  u32 u = __float_as_uint(f);
  u32 r = (u + 0x7FFFu + ((u >> 16) & 1u)) >> 16;   // RNE
  return (u16)r;
}
__device__ __forceinline__ float b2f(u16 s) {
  return __uint_as_float(((u32)s) << 16);
}

typedef __attribute__((address_space(1))) void gvoid;
typedef __attribute__((address_space(3))) void lvoid;
__device__ __forceinline__ void gl_lds16(const void* g, void* l) {
  __builtin_amdgcn_global_load_lds((gvoid*)g, (lvoid*)l, 16, 0, 0);
}

// ---------------- fp32 -> bf16 convert (for weight matrices) ----------------
__global__ void cvt_kernel(const float* __restrict__ src, u16* __restrict__ dst, int n8) {
  int i = blockIdx.x * 256 + threadIdx.x;
  if (i >= n8) return;
  const f32x4* sp = (const f32x4*)src + (size_t)i * 2;
  f32x4 a = sp[0], b = sp[1];
  alignas(16) u16 o[8];
#pragma unroll
  for (int j = 0; j < 4; ++j) { o[j] = f2bf(a[j]); o[4 + j] = f2bf(b[j]); }
  *(u32x4*)(dst + (size_t)i * 8) = *(u32x4*)o;
}

// ---------------- bf16 MFMA GEMM, C = A @ B^T  (A[M,K], B[N,K]) -------------
// MODE 0: A fp32 (activations), write bf16 TRANSPOSED out[b][n][l]  (m = b*2048 + l)
// MODE 1: A bf16, write fp32 out[m][n] + bias[n]
template<int MODE>
__global__ __launch_bounds__(256, 2) void gemm_bt(
    const void* __restrict__ Aptr, const u16* __restrict__ Bw,
    void* __restrict__ Cout, const float* __restrict__ bias)
{
  constexpr int K = 1024, N = 1024;
  __shared__ __align__(16) u16 lA[128 * 32];
  __shared__ __align__(16) u16 lB[128 * 32];

  int bx = blockIdx.x;
  int wg = (bx & 7) * 256 + (bx >> 3);        // XCD swizzle (nwg=2048, 8 | nwg)
  int tm = wg >> 3, tn = wg & 7;
  int m0 = tm * 128, n0 = tn * 128;

  int t = threadIdx.x;
  int wid = t >> 6, lane = t & 63;
  int wm = wid >> 1, wn = wid & 1;
  int lr = lane & 15, kb = lane >> 4;

  f32x4 acc[4][4] = {};

  for (int kt = 0; kt < 32; ++kt) {
    int k0 = kt * 32;
    // ---- stage A tile [128][32] ----
    if constexpr (MODE == 0) {
      const float* A = (const float*)Aptr;
      int r = t >> 1, half = t & 1;
      const float* ap = A + (size_t)(m0 + r) * K + k0 + half * 16;
      f32x4 v[4];
#pragma unroll
      for (int g = 0; g < 4; ++g) v[g] = ((const f32x4*)ap)[g];
      alignas(16) u16 o[16];
#pragma unroll
      for (int j = 0; j < 16; ++j) o[j] = f2bf(v[j >> 2][j & 3]);
      *(u32x4*)&lA[r * 32 + half * 16]     = *(u32x4*)&o[0];
      *(u32x4*)&lA[r * 32 + half * 16 + 8] = *(u32x4*)&o[8];
    } else {
      const u16* A = (const u16*)Aptr;
#pragma unroll
      for (int it = 0; it < 2; ++it) {
        int o = t * 16 + it * 4096;          // byte offset in LDS tile
        int e = o >> 1;
        int row = e >> 5, col = e & 31;
        gl_lds16(A + (size_t)(m0 + row) * K + k0 + col,
                 (char*)lA + wid * 1024 + it * 4096);
      }
    }
    // ---- stage B tile [128][32] via global_load_lds ----
#pragma unroll
    for (int it = 0; it < 2; ++it) {
      int o = t * 16 + it * 4096;
      int e = o >> 1;
      int row = e >> 5, col = e & 31;
      gl_lds16(Bw + (size_t)(n0 + row) * K + k0 + col,
               (char*)lB + wid * 1024 + it * 4096);
    }
    __syncthreads();

    s16x8 af[4], bf[4];
#pragma unroll
    for (int mi = 0; mi < 4; ++mi)
      af[mi] = *(const s16x8*)&lA[(wm * 64 + mi * 16 + lr) * 32 + kb * 8];
#pragma unroll
    for (int ni = 0; ni < 4; ++ni)
      bf[ni] = *(const s16x8*)&lB[(wn * 64 + ni * 16 + lr) * 32 + kb * 8];
#pragma unroll
    for (int mi = 0; mi < 4; ++mi)
#pragma unroll
      for (int ni = 0; ni < 4; ++ni)
        acc[mi][ni] = __builtin_amdgcn_mfma_f32_16x16x32_bf16(af[mi], bf[ni], acc[mi][ni], 0, 0, 0);
    __syncthreads();
  }

  // ---- epilogue ----
#pragma unroll
  for (int mi = 0; mi < 4; ++mi) {
    int mbase = m0 + wm * 64 + mi * 16 + kb * 4;   // C row = (lane>>4)*4 + reg
#pragma unroll
    for (int ni = 0; ni < 4; ++ni) {
      int nn = n0 + wn * 64 + ni * 16 + lr;        // C col = lane&15
      if constexpr (MODE == 0) {
        u16* OT = (u16*)Cout;
        int b = mbase >> 11, l = mbase & 2047;     // 4 consecutive l, same b
        alignas(8) u16 pk[4];
#pragma unroll
        for (int j = 0; j < 4; ++j) pk[j] = f2bf(acc[mi][ni][j]);
        *(u32x2*)(OT + ((size_t)((b << 10) + nn)) * 2048 + l) = *(u32x2*)pk;
      } else {
        float* C = (float*)Cout;
        float bv = bias[nn];
#pragma unroll
        for (int j = 0; j < 4; ++j)
          C[(size_t)(mbase + j) * N + nn] = acc[mi][ni][j] + bv;
      }
    }
  }
}

// ======================= FFT-based circular correlation =====================
// corr[row] = irfft( rfft(Q[row]) * conj(rfft(K[row])) ), L=2048.
// Packed half-size complex FFT: z[n] = x[2n] + i*x[2n+1], M=1024.
// Four-step 32x32 FFT, 32 threads/row, 8 rows per 256-thread block.
// Spectra held in registers as PACKED bf16 pairs (u32) to keep the live set
// under the 128-VGPR allocation the backend insists on (r4/r5: 4-wave target
// caused ~1.24 GB of spill traffic with full-f32 spectra).

__device__ __constant__ const int BRv[32] = {
  0,16,8,24,4,20,12,28,2,18,10,26,6,22,14,30,
  1,17,9,25,5,21,13,29,3,19,11,27,7,23,15,31};
__device__ const float C32v[16] = {
  1.0f, 0.98078528f, 0.92387953f, 0.83146961f,
  0.70710678f, 0.55557023f, 0.38268343f, 0.19509032f,
  0.0f, -0.19509032f, -0.38268343f, -0.55557023f,
  -0.70710678f, -0.83146961f, -0.92387953f, -0.98078528f};
__device__ const float S32v[16] = {
  0.0f, 0.19509032f, 0.38268343f, 0.55557023f,
  0.70710678f, 0.83146961f, 0.92387953f, 0.98078528f,
  1.0f, 0.98078528f, 0.92387953f, 0.83146961f,
  0.70710678f, 0.55557023f, 0.38268343f, 0.19509032f};

#define TWIDX(j) ((j) + ((j) >> 4))

// in-place 32-pt DIT DFT; input must be bit-reversed, output natural order.
template<bool INV>
__device__ __forceinline__ void dft32(float* xr, float* xi) {
#pragma unroll
  for (int s = 0; s < 5; ++s) {
    const int half = 1 << s, step = 16 >> s;
#pragma unroll
    for (int blk = 0; blk < 32; blk += 2 * half) {
#pragma unroll
      for (int j = 0; j < half; ++j) {
        float wr = C32v[j * step];
        float wi = INV ? S32v[j * step] : -S32v[j * step];
        int p = blk + j, q = p + half;
        float vr = xr[q] * wr - xi[q] * wi;
        float vi = xr[q] * wi + xi[q] * wr;
        xr[q] = xr[p] - vr; xi[q] = xi[p] - vi;
        xr[p] = xr[p] + vr; xi[p] = xi[p] + vi;
      }
    }
  }
}

// forward 1024-pt complex FFT of packed row (bf16 pairs as u32), four-step.
// result: thread tt holds Z[tt + 32*k2] in (xr[k2], xi[k2]).
__device__ __forceinline__ void fft_fwd_row(const u32* __restrict__ zrow, int tt,
                                            float2* wsr, const float2* tw,
                                            float* xr, float* xi) {
#pragma unroll
  for (int i = 0; i < 32; ++i) {
    u32 v = zrow[32 * BRv[i] + tt];
    xr[i] = b2f((u16)(v & 0xffffu));
    xi[i] = b2f((u16)(v >> 16));
  }
  dft32<false>(xr, xi);
#pragma unroll
  for (int k1 = 0; k1 < 32; ++k1) {
    float2 w = tw[TWIDX(tt * k1)];               // e^{-2pi i * tt*k1/1024}
    float2 o;
    o.x = xr[k1] * w.x - xi[k1] * w.y;
    o.y = xr[k1] * w.y + xi[k1] * w.x;
    wsr[k1 * 33 + tt] = o;
  }
  __syncthreads();
#pragma unroll
  for (int i = 0; i < 32; ++i) {
    float2 v = wsr[tt * 33 + BRv[i]];
    xr[i] = v.x; xi[i] = v.y;
  }
  __syncthreads();
  dft32<false>(xr, xi);
}

// one spectral bin: Zl/Zp are Z[k], Z[M-k] (pre-conj) for Q and K; W = e^{-i pi k/M}.
// out = Zc[k] * (1/1024), with all 0.5 factors folded (total 1/8192 on unscaled G's).
__device__ __forceinline__ void spec_bin(
    float zlQr, float zlQi, float zpQr, float zpQi,
    float zlKr, float zlKi, float zpKr, float zpKi,
    float wr, float wi, float& outr, float& outi)
{
  // A2 = Zl + conj(Zp), B2 = Zl - conj(Zp); G = A2 - i*W*B2 (=2*X[k])
  float aQr = zlQr + zpQr, aQi = zlQi - zpQi;
  float bQr = zlQr - zpQr, bQi = zlQi + zpQi;
  float gQr  = aQr + wr * bQi + wi * bQr;
  float gQi  = aQi - (wr * bQr - wi * bQi);
  float gQpr = aQr - wr * bQi - wi * bQr;       // 2*X[M-k]
  float gQpi = -aQi - wr * bQr + wi * bQi;
  float aKr = zlKr + zpKr, aKi = zlKi - zpKi;
  float bKr = zlKr - zpKr, bKi = zlKi + zpKi;
  float gKr  = aKr + wr * bKi + wi * bKr;
  float gKi  = aKi - (wr * bKr - wi * bKi);
  float gKpr = aKr - wr * bKi - wi * bKr;
  float gKpi = -aKi - wr * bKr + wi * bKi;
  // Ct = Gq*conj(Gk) (=4*C[k]); CPt = Gq'*conj(Gk') (=4*C[M-k])
  float ctr = gQr * gKr + gQi * gKi;
  float cti = gQi * gKr - gQr * gKi;
  float cpr = gQpr * gKpr + gQpi * gKpi;
  float cpi = gQpi * gKpr - gQpr * gKpi;
  // Zc = 0.5*(Ut + i*conj(W)*Vt)/4 /1024  => *(1/8192)
  float utr = ctr + cpr, uti = cti - cpi;
  float vtr = ctr - cpr, vti = cti + cpi;
  outr = (utr - wr * vti + wi * vtr) * (1.0f / 8192.0f);
  outi = (uti + wr * vtr + wi * vti) * (1.0f / 8192.0f);
}

__global__ __launch_bounds__(256) void fftcorr_kernel(
    const u16* __restrict__ Qt, const u16* __restrict__ Kt, float* __restrict__ corr)
{
  __shared__ float2 tw[1088];        // e^{-2pi i j/1024}, padded idx j+(j>>4)
  __shared__ float2 wsb[8][1056];    // per-row 32x33 exchange buffer

  int t = threadIdx.x;
#pragma unroll
  for (int i = 0; i < 4; ++i) {
    int j = t + 256 * i;
    float s, c;
    __sincosf((float)j * -6.135923151e-3f, &s, &c);   // -2*pi/1024
    float2 w; w.x = c; w.y = s;
    tw[TWIDX(j)] = w;
  }
  __syncthreads();

  int rl = t >> 5, tt = t & 31;
  int row = blockIdx.x * 8 + rl;
  const u32* qrow = (const u32*)Qt + (size_t)row * 1024;
  const u32* krow = (const u32*)Kt + (size_t)row * 1024;
  float2* wsr = wsb[rl];
  int lw = t & 63;
  int paddr = (((-tt) & 31) | (lw & 32)) << 2;   // partner lane (M-k pairing)
  bool f0 = (tt == 0);

  float xr[32], xi[32];            // FFT working set (reused K then Q)
  u32 zkp[32], ap[32];             // PACKED spectra: lo16=re, hi16=im (bf16)
  float zcr[32], zci[32];

  fft_fwd_row(krow, tt, wsr, tw, xr, xi);
#pragma unroll
  for (int i = 0; i < 32; ++i)
    zkp[i] = ((u32)f2bf(xi[i]) << 16) | (u32)f2bf(xr[i]);
  fft_fwd_row(qrow, tt, wsr, tw, xr, xi);
#pragma unroll
  for (int i = 0; i < 32; ++i)
    ap[i] = ((u32)f2bf(xi[i]) << 16) | (u32)f2bf(xr[i]);

  // spectral: C = Xq * conj(Xk), repack to packed inverse spectrum Zc
#pragma unroll
  for (int j = 0; j < 16; ++j) {
    // bin A: k = tt + 32*j (packed slot j); bin B: k = tt + 32*(31-j) (slot 31-j)
    u32 qpA = (u32)__builtin_amdgcn_ds_bpermute(paddr, (int)ap[31 - j]);
    u32 kpA = (u32)__builtin_amdgcn_ds_bpermute(paddr, (int)zkp[31 - j]);
    u32 qpB = (u32)__builtin_amdgcn_ds_bpermute(paddr, (int)ap[j]);
    u32 kpB = (u32)__builtin_amdgcn_ds_bpermute(paddr, (int)zkp[j]);
    if (f0) {  // lane 0: partner is itself with k2-wrap instead of lane-wrap
      qpA = ap[(32 - j) & 31];  kpA = zkp[(32 - j) & 31];
      qpB = ap[(j + 1) & 31];   kpB = zkp[(j + 1) & 31];
    }
    // W = e^{-i pi k/1024}: tw[k>>1] (* e^{-i pi/1024} if k odd; odd iff tt odd)
    float2 bA = tw[TWIDX((tt >> 1) + 16 * j)];
    float2 bB = tw[TWIDX((tt >> 1) + 16 * (31 - j))];
    bool oddk = (tt & 1);
    float mr = oddk ? 0.999995293810f : 1.0f;
    float mi = oddk ? -3.067956763e-3f : 0.0f;
    float wAr = bA.x * mr - bA.y * mi, wAi = bA.x * mi + bA.y * mr;
    float wBr = bB.x * mr - bB.y * mi, wBi = bB.x * mi + bB.y * mr;
    spec_bin(b2f((u16)ap[j]), b2f((u16)(ap[j] >> 16)),
             b2f((u16)qpA),   b2f((u16)(qpA >> 16)),
             b2f((u16)zkp[j]), b2f((u16)(zkp[j] >> 16)),
             b2f((u16)kpA),   b2f((u16)(kpA >> 16)),
             wAr, wAi, zcr[j], zci[j]);
    spec_bin(b2f((u16)ap[31 - j]), b2f((u16)(ap[31 - j] >> 16)),
             b2f((u16)qpB),        b2f((u16)(qpB >> 16)),
             b2f((u16)zkp[31 - j]), b2f((u16)(zkp[31 - j] >> 16)),
             b2f((u16)kpB),        b2f((u16)(kpB >> 16)),
             wBr, wBi, zcr[31 - j], zci[31 - j]);
  }

  // inverse 1024-pt FFT of Zc (unscaled; 1/1024 already folded above)
#define SWP(a, b) { float t1 = zcr[a]; zcr[a] = zcr[b]; zcr[b] = t1; \
                    float t2 = zci[a]; zci[a] = zci[b]; zci[b] = t2; }
  SWP(1, 16) SWP(2, 8) SWP(3, 24) SWP(5, 20) SWP(6, 12) SWP(7, 28)
  SWP(9, 18) SWP(11, 26) SWP(13, 22) SWP(15, 30) SWP(19, 25) SWP(23, 29)
#undef SWP
  dft32<true>(zcr, zci);
#pragma unroll
  for (int v1 = 0; v1 < 32; ++v1) {
    float2 w = tw[TWIDX(tt * v1)];               // conj -> e^{+2pi i tt*v1/1024}
    float2 o;
    o.x = zcr[v1] * w.x + zci[v1] * w.y;
    o.y = zci[v1] * w.x - zcr[v1] * w.y;
    wsr[v1 * 33 + tt] = o;
  }
  __syncthreads();
#pragma unroll
  for (int i = 0; i < 32; ++i) {
    float2 v = wsr[tt * 33 + BRv[i]];
    zcr[i] = v.x; zci[i] = v.y;
  }
  dft32<true>(zcr, zci);

  // zc[n]: thread tt holds n = tt + 32*v2 -> corr[2n]=Re, corr[2n+1]=Im
  float2* crow = (float2*)(corr + (size_t)row * 2048);
#pragma unroll
  for (int v2 = 0; v2 < 32; ++v2) {
    float2 o; o.x = zcr[v2]; o.y = zci[v2];
    crow[tt + 32 * v2] = o;
  }
}

// ---------------- mean over heads: corr[b][h*64+d][l] -> mean[b][d][l] ------
__global__ void mean_kernel(const float* __restrict__ corr, float* __restrict__ meanp) {
  int idx = blockIdx.x * 256 + threadIdx.x;   // 524288 float4 groups
  int l4 = idx & 511;
  int d  = (idx >> 9) & 63;
  int b  = idx >> 15;
  const f32x4* cp = (const f32x4*)corr;
  f32x4 s = {};
#pragma unroll
  for (int h = 0; h < 16; ++h)
    s += cp[((size_t)(b * 1024 + h * 64 + d)) * 512 + l4];
  ((f32x4*)meanp)[(size_t)(b * 64 + d) * 512 + l4] = s * 0.0625f;
}

// ---------------- top-7 + softmax per (b,d) row -----------------------------
__global__ __launch_bounds__(256) void topk_kernel(
    const float* __restrict__ meanp, int* __restrict__ delays, float* __restrict__ wts)
{
  int row = blockIdx.x;                        // b*64 + d  (consumed as h*64 + d)
  const float* mr = meanp + (size_t)row * 2048;
  int t = threadIdx.x;
  float v[8];
#pragma unroll
  for (int j = 0; j < 8; ++j) v[j] = mr[t * 8 + j];
  __shared__ float sV[256];
  __shared__ int   sI[256];
  __shared__ float topv[TOPK];
  __shared__ int   topi[TOPK];
  for (int rnd = 0; rnd < TOPK; ++rnd) {
    float bv = v[0]; int bi = t * 8;
#pragma unroll
    for (int j = 1; j < 8; ++j)
      if (v[j] > bv) { bv = v[j]; bi = t * 8 + j; }   // strict > : ties keep lowest idx
    sV[t] = bv; sI[t] = bi;
    __syncthreads();
    for (int off = 128; off > 0; off >>= 1) {
      if (t < off) {
        float ov = sV[t + off]; int oi = sI[t + off];
        if (ov > sV[t] || (ov == sV[t] && oi < sI[t])) { sV[t] = ov; sI[t] = oi; }
      }
      __syncthreads();
    }
    int wi = sI[0];
    if (t == 0) { topv[rnd] = sV[0]; topi[rnd] = wi; }
    if ((wi >> 3) == t) {
#pragma unroll
      for (int j = 0; j < 8; ++j)                    // static idx (no scratch)
        if ((wi & 7) == j) v[j] = -__builtin_inff();
    }
    __syncthreads();
  }
  if (t == 0) {
    float mx = topv[0], sum = 0.f, e[TOPK];
#pragma unroll
    for (int i = 0; i < TOPK; ++i) { e[i] = expf(topv[i] - mx); sum += e[i]; }
#pragma unroll
    for (int i = 0; i < TOPK; ++i) {
      wts[row * 8 + i]    = e[i] / sum;
      delays[row * 8 + i] = topi[i];
    }
  }
}

// ---------------- delay-roll aggregation: aggt[b][c][l] ---------------------
__global__ __launch_bounds__(256) void agg_kernel(
    const u16* __restrict__ Vt, const float* __restrict__ wts,
    const int* __restrict__ delays, u16* __restrict__ aggt)
{
  int row = blockIdx.x;           // b*1024 + c
  int c = row & 1023;             // weights index: (c>>6)*64 + (c&63) == c
  __shared__ __align__(16) float Vs[4608];
  __shared__ float wsh[TOPK];
  __shared__ int   dsh[TOPK];
  int t = threadIdx.x;
  if (t < TOPK) { wsh[t] = wts[c * 8 + t]; dsh[t] = delays[c * 8 + t]; }
  const u16* vr = Vt + (size_t)row * 2048;
  u32x4 rv = *(const u32x4*)(vr + t * 8);
  alignas(16) u16 uv[8];
  *(u32x4*)uv = rv;
  int f0 = t * 8;
#pragma unroll
  for (int j = 0; j < 8; ++j) {
    float fv = b2f(uv[j]);
    int f  = f0 + j;
    int f2 = f + 2048;
    Vs[f  + ((f  >> 5) << 2)] = fv;
    Vs[f2 + ((f2 >> 5) << 2)] = fv;
  }
  __syncthreads();
  float o[8] = {0, 0, 0, 0, 0, 0, 0, 0};
#pragma unroll
  for (int i = 0; i < TOPK; ++i) {
    float w = wsh[i]; int dl = dsh[i];
    int base = f0 + dl;
#pragma unroll
    for (int j = 0; j < 8; ++j) {
      int f = base + j;                       // <= 4094, dup covers mod L
      o[j] += w * Vs[f + ((f >> 5) << 2)];
    }
  }
  alignas(16) u16 ob[8];
#pragma unroll
  for (int j = 0; j < 8; ++j) ob[j] = f2bf(o[j]);
  *(u32x4*)(aggt + (size_t)row * 2048 + f0) = *(u32x4*)ob;
}

// ---------------- transpose aggt[b][c][l] -> aggb[b][l][c] (bf16) -----------
__global__ __launch_bounds__(256) void transpose_kernel(
    const u16* __restrict__ aggt, u16* __restrict__ aggb)
{
  int bid = blockIdx.x;
  int lt = bid & 31;
  int ct = (bid >> 5) & 15;
  int b  = bid >> 9;
  __shared__ __align__(16) u16 tile[64][72];
  int t = threadIdx.x;
  int r = t >> 2, seg = t & 3;
  const u16* src = aggt + ((size_t)(b * 1024 + ct * 64 + r)) * 2048 + lt * 64 + seg * 16;
  u32x4 v0 = *(const u32x4*)src;
  u32x4 v1 = *(const u32x4*)(src + 8);
  *(u32x4*)&tile[r][seg * 16]     = v0;
  *(u32x4*)&tile[r][seg * 16 + 8] = v1;
  __syncthreads();
  alignas(16) u16 tmp[16];
#pragma unroll
  for (int j = 0; j < 16; ++j) tmp[j] = tile[seg * 16 + j][r];
  u16* dst = aggb + ((size_t)(b * 2048 + lt * 64 + r)) * 1024 + ct * 64 + seg * 16;
  *(u32x4*)dst       = *(u32x4*)&tmp[0];
  *(u32x4*)(dst + 8) = *(u32x4*)&tmp[8];
}

// ---------------------------------------------------------------------------
extern "C" void kernel_launch(void* const* d_in, const int* in_sizes, int n_in,
                              void* d_out, int out_size, void* d_ws, size_t ws_size,
                              hipStream_t stream) {
  (void)in_sizes; (void)n_in; (void)out_size; (void)ws_size;
  const float* qin = (const float*)d_in[0];
  const float* kin = (const float*)d_in[1];
  const float* vin = (const float*)d_in[2];
  const float* Wq  = (const float*)d_in[3];
  const float* Wk  = (const float*)d_in[4];
  const float* Wv  = (const float*)d_in[5];
  const float* Wo  = (const float*)d_in[6];
  const float* bo  = (const float*)d_in[7];

  float* out  = (float*)d_out;                  // [16][2048][1024] fp32
  float* corr = out + (size_t)33554432;         // [16][1024][2048] fp32

  char* ws = (char*)d_ws;
  u16* Qt  = (u16*)ws;                                   // 64 MiB  [16][1024][2048] bf16
  u16* Kt  = (u16*)(ws + ((size_t)64  << 20));           // 64 MiB
  u16* Vt  = (u16*)(ws + ((size_t)128 << 20));           // 64 MiB
  u16* Wqb = (u16*)(ws + ((size_t)192 << 20));           // 2 MiB each
  u16* Wkb = Wqb + (1u << 20);
  u16* Wvb = Wkb + (1u << 20);
  u16* Wob = Wvb + (1u << 20);
  float* meanp  = (float*)(ws + ((size_t)200 << 20));    // 8 MiB [16][64][2048] fp32
  int*   delays = (int*)  (ws + ((size_t)208 << 20));    // [1024][8]
  float* wts    = (float*)(ws + ((size_t)208 << 20) + 65536);
  u16* aggt = Qt;   // reuse (Qt dead after corr)
  u16* aggb = Kt;   // reuse (Kt dead after corr)

  dim3 blk(256);
  cvt_kernel<<<512, blk, 0, stream>>>(Wq, Wqb, 131072);
  cvt_kernel<<<512, blk, 0, stream>>>(Wk, Wkb, 131072);
  cvt_kernel<<<512, blk, 0, stream>>>(Wv, Wvb, 131072);
  cvt_kernel<<<512, blk, 0, stream>>>(Wo, Wob, 131072);

  gemm_bt<0><<<2048, blk, 0, stream>>>(qin, Wqb, Qt, nullptr);
  gemm_bt<0><<<2048, blk, 0, stream>>>(kin, Wkb, Kt, nullptr);
  gemm_bt<0><<<2048, blk, 0, stream>>>(vin, Wvb, Vt, nullptr);

  fftcorr_kernel<<<2048, blk, 0, stream>>>(Qt, Kt, corr);
  mean_kernel<<<2048, blk, 0, stream>>>(corr, meanp);
  topk_kernel<<<1024, blk, 0, stream>>>(meanp, delays, wts);
  agg_kernel<<<16384, blk, 0, stream>>>(Vt, wts, delays, aggt);
  transpose_kernel<<<8192, blk, 0, stream>>>(aggt, aggb);
  gemm_bt<1><<<2048, blk, 0, stream>>>(aggb, Wob, out, bo);
}

// Round 7
// 756.106 us; speedup vs baseline: 1.4323x; 1.0926x over previous
//
#include <hip/hip_runtime.h>
#include <hip/hip_fp16.h>
#include <cstdint>
#include <cstddef>

typedef float  f32x4 __attribute__((ext_vector_type(4)));
typedef short  s16x8 __attribute__((ext_vector_type(8)));
typedef unsigned short u16;
typedef unsigned int   u32;
typedef u32 u32x4 __attribute__((ext_vector_type(4)));
typedef u32 u32x2 __attribute__((ext_vector_type(2)));

#define TOPK 7

__device__ __forceinline__ u16 f2bf(float f) {
  u32 u = __float_as_uint(f);
  u32 r = (u + 0x7FFFu + ((u >> 16) & 1u)) >> 16;   // RNE
  return (u16)r;
}
__device__ __forceinline__ float b2f(u16 s) {
  return __uint_as_float(((u32)s) << 16);
}
__device__ __forceinline__ u32 bfpk(float re, float im) {
  return ((u32)f2bf(im) << 16) | (u32)f2bf(re);
}
__device__ __forceinline__ float2 bfup(u32 p) {
  float2 r; r.x = b2f((u16)(p & 0xffffu)); r.y = b2f((u16)(p >> 16)); return r;
}
__device__ __forceinline__ u32 pkf16(float c, float s) {
  __half2 h = __floats2half2_rn(c, s);
  return *(u32*)&h;
}
__device__ __forceinline__ float2 upf16(u32 p) {
  __half2 h; *(u32*)&h = p;
  float2 r; r.x = __low2float(h); r.y = __high2float(h); return r;
}

typedef __attribute__((address_space(1))) void gvoid;
typedef __attribute__((address_space(3))) void lvoid;
__device__ __forceinline__ void gl_lds16(const void* g, void* l) {
  __builtin_amdgcn_global_load_lds((gvoid*)g, (lvoid*)l, 16, 0, 0);
}

// ---------------- fp32 -> bf16 convert (for weight matrices) ----------------
__global__ void cvt_kernel(const float* __restrict__ src, u16* __restrict__ dst, int n8) {
  int i = blockIdx.x * 256 + threadIdx.x;
  if (i >= n8) return;
  const f32x4* sp = (const f32x4*)src + (size_t)i * 2;
  f32x4 a = sp[0], b = sp[1];
  alignas(16) u16 o[8];
#pragma unroll
  for (int j = 0; j < 4; ++j) { o[j] = f2bf(a[j]); o[4 + j] = f2bf(b[j]); }
  *(u32x4*)(dst + (size_t)i * 8) = *(u32x4*)o;
}

// ---------------- bf16 MFMA GEMM, C = A @ B^T  (A[M,K], B[N,K]) -------------
// MODE 0: A fp32 (activations), write bf16 TRANSPOSED out[b][n][l]  (m = b*2048 + l)
// MODE 1: A bf16, write fp32 out[m][n] + bias[n]
template<int MODE>
__global__ __launch_bounds__(256, 2) void gemm_bt(
    const void* __restrict__ Aptr, const u16* __restrict__ Bw,
    void* __restrict__ Cout, const float* __restrict__ bias)
{
  constexpr int K = 1024, N = 1024;
  __shared__ __align__(16) u16 lA[128 * 32];
  __shared__ __align__(16) u16 lB[128 * 32];

  int bx = blockIdx.x;
  int wg = (bx & 7) * 256 + (bx >> 3);        // XCD swizzle (nwg=2048, 8 | nwg)
  int tm = wg >> 3, tn = wg & 7;
  int m0 = tm * 128, n0 = tn * 128;

  int t = threadIdx.x;
  int wid = t >> 6, lane = t & 63;
  int wm = wid >> 1, wn = wid & 1;
  int lr = lane & 15, kb = lane >> 4;

  f32x4 acc[4][4] = {};

  for (int kt = 0; kt < 32; ++kt) {
    int k0 = kt * 32;
    // ---- stage A tile [128][32] ----
    if constexpr (MODE == 0) {
      const float* A = (const float*)Aptr;
      int r = t >> 1, half = t & 1;
      const float* ap = A + (size_t)(m0 + r) * K + k0 + half * 16;
      f32x4 v[4];
#pragma unroll
      for (int g = 0; g < 4; ++g) v[g] = ((const f32x4*)ap)[g];
      alignas(16) u16 o[16];
#pragma unroll
      for (int j = 0; j < 16; ++j) o[j] = f2bf(v[j >> 2][j & 3]);
      *(u32x4*)&lA[r * 32 + half * 16]     = *(u32x4*)&o[0];
      *(u32x4*)&lA[r * 32 + half * 16 + 8] = *(u32x4*)&o[8];
    } else {
      const u16* A = (const u16*)Aptr;
#pragma unroll
      for (int it = 0; it < 2; ++it) {
        int o = t * 16 + it * 4096;          // byte offset in LDS tile
        int e = o >> 1;
        int row = e >> 5, col = e & 31;
        gl_lds16(A + (size_t)(m0 + row) * K + k0 + col,
                 (char*)lA + wid * 1024 + it * 4096);
      }
    }
    // ---- stage B tile [128][32] via global_load_lds ----
#pragma unroll
    for (int it = 0; it < 2; ++it) {
      int o = t * 16 + it * 4096;
      int e = o >> 1;
      int row = e >> 5, col = e & 31;
      gl_lds16(Bw + (size_t)(n0 + row) * K + k0 + col,
               (char*)lB + wid * 1024 + it * 4096);
    }
    __syncthreads();

    s16x8 af[4], bf[4];
#pragma unroll
    for (int mi = 0; mi < 4; ++mi)
      af[mi] = *(const s16x8*)&lA[(wm * 64 + mi * 16 + lr) * 32 + kb * 8];
#pragma unroll
    for (int ni = 0; ni < 4; ++ni)
      bf[ni] = *(const s16x8*)&lB[(wn * 64 + ni * 16 + lr) * 32 + kb * 8];
#pragma unroll
    for (int mi = 0; mi < 4; ++mi)
#pragma unroll
      for (int ni = 0; ni < 4; ++ni)
        acc[mi][ni] = __builtin_amdgcn_mfma_f32_16x16x32_bf16(af[mi], bf[ni], acc[mi][ni], 0, 0, 0);
    __syncthreads();
  }

  // ---- epilogue ----
#pragma unroll
  for (int mi = 0; mi < 4; ++mi) {
    int mbase = m0 + wm * 64 + mi * 16 + kb * 4;   // C row = (lane>>4)*4 + reg
#pragma unroll
    for (int ni = 0; ni < 4; ++ni) {
      int nn = n0 + wn * 64 + ni * 16 + lr;        // C col = lane&15
      if constexpr (MODE == 0) {
        u16* OT = (u16*)Cout;
        int b = mbase >> 11, l = mbase & 2047;     // 4 consecutive l, same b
        alignas(8) u16 pk[4];
#pragma unroll
        for (int j = 0; j < 4; ++j) pk[j] = f2bf(acc[mi][ni][j]);
        *(u32x2*)(OT + ((size_t)((b << 10) + nn)) * 2048 + l) = *(u32x2*)pk;
      } else {
        float* C = (float*)Cout;
        float bv = bias[nn];
#pragma unroll
        for (int j = 0; j < 4; ++j)
          C[(size_t)(mbase + j) * N + nn] = acc[mi][ni][j] + bv;
      }
    }
  }
}

// ======================= FFT-based circular correlation =====================
// corr[row] = irfft( rfft(Q[row]) * conj(rfft(K[row])) ), L=2048.
// Packed half-size complex FFT: z[n] = x[2n] + i*x[2n+1], M=1024.
// Four-step 32x32 FFT, 32 threads/row, 8 rows per 256-thread block.
// All register spectra AND the LDS exchange buffers are packed bf16 pairs;
// twiddles are packed f16 pairs. This keeps VGPR <= ~128 (r4/r5: f32 spectra
// spilled 1.2 GB) and LDS at ~37 KB -> 4 blocks/CU (r6 at 76 KB was 2).

__device__ __constant__ const int BRv[32] = {
  0,16,8,24,4,20,12,28,2,18,10,26,6,22,14,30,
  1,17,9,25,5,21,13,29,3,19,11,27,7,23,15,31};
__device__ const float C32v[16] = {
  1.0f, 0.98078528f, 0.92387953f, 0.83146961f,
  0.70710678f, 0.55557023f, 0.38268343f, 0.19509032f,
  0.0f, -0.19509032f, -0.38268343f, -0.55557023f,
  -0.70710678f, -0.83146961f, -0.92387953f, -0.98078528f};
__device__ const float S32v[16] = {
  0.0f, 0.19509032f, 0.38268343f, 0.55557023f,
  0.70710678f, 0.83146961f, 0.92387953f, 0.98078528f,
  1.0f, 0.98078528f, 0.92387953f, 0.83146961f,
  0.70710678f, 0.55557023f, 0.38268343f, 0.19509032f};

#define TWIDX(j) ((j) + ((j) >> 4))

// in-place 32-pt DIT DFT; input must be bit-reversed, output natural order.
template<bool INV>
__device__ __forceinline__ void dft32(float* xr, float* xi) {
#pragma unroll
  for (int s = 0; s < 5; ++s) {
    const int half = 1 << s, step = 16 >> s;
#pragma unroll
    for (int blk = 0; blk < 32; blk += 2 * half) {
#pragma unroll
      for (int j = 0; j < half; ++j) {
        float wr = C32v[j * step];
        float wi = INV ? S32v[j * step] : -S32v[j * step];
        int p = blk + j, q = p + half;
        float vr = xr[q] * wr - xi[q] * wi;
        float vi = xr[q] * wi + xi[q] * wr;
        xr[q] = xr[p] - vr; xi[q] = xi[p] - vi;
        xr[p] = xr[p] + vr; xi[p] = xi[p] + vi;
      }
    }
  }
}

// forward 1024-pt complex FFT of packed row (bf16 pairs as u32), four-step.
// result: thread tt holds Z[tt + 32*k2] in (xr[k2], xi[k2]).
__device__ __forceinline__ void fft_fwd_row(const u32* __restrict__ zrow, int tt,
                                            u32* wsr, const u32* twp,
                                            float* xr, float* xi) {
#pragma unroll
  for (int i = 0; i < 32; ++i) {
    float2 v = bfup(zrow[32 * BRv[i] + tt]);
    xr[i] = v.x; xi[i] = v.y;
  }
  dft32<false>(xr, xi);
#pragma unroll
  for (int k1 = 0; k1 < 32; ++k1) {
    float2 w = upf16(twp[TWIDX(tt * k1)]);       // e^{-2pi i * tt*k1/1024}
    wsr[k1 * 33 + tt] = bfpk(xr[k1] * w.x - xi[k1] * w.y,
                             xr[k1] * w.y + xi[k1] * w.x);
  }
  __syncthreads();
#pragma unroll
  for (int i = 0; i < 32; ++i) {
    float2 v = bfup(wsr[tt * 33 + BRv[i]]);
    xr[i] = v.x; xi[i] = v.y;
  }
  __syncthreads();
  dft32<false>(xr, xi);
}

// one spectral bin: Zl/Zp are Z[k], Z[M-k] (pre-conj) for Q and K; W = e^{-i pi k/M}.
// out = Zc[k] * (1/1024), with all 0.5 factors folded (total 1/8192 on unscaled G's).
__device__ __forceinline__ void spec_bin(
    float zlQr, float zlQi, float zpQr, float zpQi,
    float zlKr, float zlKi, float zpKr, float zpKi,
    float wr, float wi, float& outr, float& outi)
{
  // A2 = Zl + conj(Zp), B2 = Zl - conj(Zp); G = A2 - i*W*B2 (=2*X[k])
  float aQr = zlQr + zpQr, aQi = zlQi - zpQi;
  float bQr = zlQr - zpQr, bQi = zlQi + zpQi;
  float gQr  = aQr + wr * bQi + wi * bQr;
  float gQi  = aQi - (wr * bQr - wi * bQi);
  float gQpr = aQr - wr * bQi - wi * bQr;       // 2*X[M-k]
  float gQpi = -aQi - wr * bQr + wi * bQi;
  float aKr = zlKr + zpKr, aKi = zlKi - zpKi;
  float bKr = zlKr - zpKr, bKi = zlKi + zpKi;
  float gKr  = aKr + wr * bKi + wi * bKr;
  float gKi  = aKi - (wr * bKr - wi * bKi);
  float gKpr = aKr - wr * bKi - wi * bKr;
  float gKpi = -aKi - wr * bKr + wi * bKi;
  // Ct = Gq*conj(Gk) (=4*C[k]); CPt = Gq'*conj(Gk') (=4*C[M-k])
  float ctr = gQr * gKr + gQi * gKi;
  float cti = gQi * gKr - gQr * gKi;
  float cpr = gQpr * gKpr + gQpi * gKpi;
  float cpi = gQpi * gKpr - gQpr * gKpi;
  // Zc = 0.5*(Ut + i*conj(W)*Vt)/4 /1024  => *(1/8192)
  float utr = ctr + cpr, uti = cti - cpi;
  float vtr = ctr - cpr, vti = cti + cpi;
  outr = (utr - wr * vti + wi * vtr) * (1.0f / 8192.0f);
  outi = (uti + wr * vtr + wi * vti) * (1.0f / 8192.0f);
}

__global__ __launch_bounds__(256) void fftcorr_kernel(
    const u16* __restrict__ Qt, const u16* __restrict__ Kt, float* __restrict__ corr)
{
  __shared__ u32 twp[1088];          // f16 (cos|sin), padded idx j+(j>>4)
  __shared__ u32 wsb[8][1056];       // per-row 32x33 exchange, bf16 (re|im)

  int t = threadIdx.x;
#pragma unroll
  for (int i = 0; i < 4; ++i) {
    int j = t + 256 * i;
    float s, c;
    __sincosf((float)j * -6.135923151e-3f, &s, &c);   // -2*pi/1024
    twp[TWIDX(j)] = pkf16(c, s);
  }
  __syncthreads();

  int rl = t >> 5, tt = t & 31;
  int row = blockIdx.x * 8 + rl;
  const u32* qrow = (const u32*)Qt + (size_t)row * 1024;
  const u32* krow = (const u32*)Kt + (size_t)row * 1024;
  u32* wsr = wsb[rl];
  int lw = t & 63;
  int paddr = (((-tt) & 31) | (lw & 32)) << 2;   // partner lane (M-k pairing)
  bool f0 = (tt == 0);

  float xr[32], xi[32];            // FFT working set (K fwd, Q fwd, inverse)
  u32 zkp[32], ap[32], zcp[32];    // PACKED spectra: lo16=re, hi16=im (bf16)

  fft_fwd_row(krow, tt, wsr, twp, xr, xi);
#pragma unroll
  for (int i = 0; i < 32; ++i) zkp[i] = bfpk(xr[i], xi[i]);
  fft_fwd_row(qrow, tt, wsr, twp, xr, xi);
#pragma unroll
  for (int i = 0; i < 32; ++i) ap[i] = bfpk(xr[i], xi[i]);

  // spectral: C = Xq * conj(Xk), repack to packed inverse spectrum Zc
#pragma unroll
  for (int j = 0; j < 16; ++j) {
    // bin A: k = tt + 32*j (packed slot j); bin B: k = tt + 32*(31-j) (slot 31-j)
    u32 qpA = (u32)__builtin_amdgcn_ds_bpermute(paddr, (int)ap[31 - j]);
    u32 kpA = (u32)__builtin_amdgcn_ds_bpermute(paddr, (int)zkp[31 - j]);
    u32 qpB = (u32)__builtin_amdgcn_ds_bpermute(paddr, (int)ap[j]);
    u32 kpB = (u32)__builtin_amdgcn_ds_bpermute(paddr, (int)zkp[j]);
    if (f0) {  // lane 0: partner is itself with k2-wrap instead of lane-wrap
      qpA = ap[(32 - j) & 31];  kpA = zkp[(32 - j) & 31];
      qpB = ap[(j + 1) & 31];   kpB = zkp[(j + 1) & 31];
    }
    // W = e^{-i pi k/1024}: tw[k>>1] (* e^{-i pi/1024} if k odd; odd iff tt odd)
    float2 bA = upf16(twp[TWIDX((tt >> 1) + 16 * j)]);
    float2 bB = upf16(twp[TWIDX((tt >> 1) + 16 * (31 - j))]);
    bool oddk = (tt & 1);
    float mr = oddk ? 0.999995293810f : 1.0f;
    float mi = oddk ? -3.067956763e-3f : 0.0f;
    float wAr = bA.x * mr - bA.y * mi, wAi = bA.x * mi + bA.y * mr;
    float wBr = bB.x * mr - bB.y * mi, wBi = bB.x * mi + bB.y * mr;
    float2 zl, zp, kl, kp;
    float or_, oi_;
    zl = bfup(ap[j]);      zp = bfup(qpA);
    kl = bfup(zkp[j]);     kp = bfup(kpA);
    spec_bin(zl.x, zl.y, zp.x, zp.y, kl.x, kl.y, kp.x, kp.y, wAr, wAi, or_, oi_);
    zcp[j] = bfpk(or_, oi_);
    zl = bfup(ap[31 - j]); zp = bfup(qpB);
    kl = bfup(zkp[31 - j]); kp = bfup(kpB);
    spec_bin(zl.x, zl.y, zp.x, zp.y, kl.x, kl.y, kp.x, kp.y, wBr, wBi, or_, oi_);
    zcp[31 - j] = bfpk(or_, oi_);
  }

  // inverse 1024-pt FFT of Zc (unscaled; 1/1024 already folded above)
#define SWPU(a, b) { u32 tp = zcp[a]; zcp[a] = zcp[b]; zcp[b] = tp; }
  SWPU(1, 16) SWPU(2, 8) SWPU(3, 24) SWPU(5, 20) SWPU(6, 12) SWPU(7, 28)
  SWPU(9, 18) SWPU(11, 26) SWPU(13, 22) SWPU(15, 30) SWPU(19, 25) SWPU(23, 29)
#undef SWPU
#pragma unroll
  for (int i = 0; i < 32; ++i) {
    float2 v = bfup(zcp[i]);
    xr[i] = v.x; xi[i] = v.y;
  }
  dft32<true>(xr, xi);
#pragma unroll
  for (int v1 = 0; v1 < 32; ++v1) {
    float2 w = upf16(twp[TWIDX(tt * v1)]);       // conj -> e^{+2pi i tt*v1/1024}
    wsr[v1 * 33 + tt] = bfpk(xr[v1] * w.x + xi[v1] * w.y,
                             xi[v1] * w.x - xr[v1] * w.y);
  }
  __syncthreads();
#pragma unroll
  for (int i = 0; i < 32; ++i) {
    float2 v = bfup(wsr[tt * 33 + BRv[i]]);
    xr[i] = v.x; xi[i] = v.y;
  }
  dft32<true>(xr, xi);

  // zc[n]: thread tt holds n = tt + 32*v2 -> corr[2n]=Re, corr[2n+1]=Im
  float2* crow = (float2*)(corr + (size_t)row * 2048);
#pragma unroll
  for (int v2 = 0; v2 < 32; ++v2) {
    float2 o; o.x = xr[v2]; o.y = xi[v2];
    crow[tt + 32 * v2] = o;
  }
}

// ---------------- mean over heads: corr[b][h*64+d][l] -> mean[b][d][l] ------
__global__ void mean_kernel(const float* __restrict__ corr, float* __restrict__ meanp) {
  int idx = blockIdx.x * 256 + threadIdx.x;   // 524288 float4 groups
  int l4 = idx & 511;
  int d  = (idx >> 9) & 63;
  int b  = idx >> 15;
  const f32x4* cp = (const f32x4*)corr;
  f32x4 s = {};
#pragma unroll
  for (int h = 0; h < 16; ++h)
    s += cp[((size_t)(b * 1024 + h * 64 + d)) * 512 + l4];
  ((f32x4*)meanp)[(size_t)(b * 64 + d) * 512 + l4] = s * 0.0625f;
}

// ---------------- top-7 + softmax per (b,d) row -----------------------------
__global__ __launch_bounds__(256) void topk_kernel(
    const float* __restrict__ meanp, int* __restrict__ delays, float* __restrict__ wts)
{
  int row = blockIdx.x;                        // b*64 + d  (consumed as h*64 + d)
  const float* mr = meanp + (size_t)row * 2048;
  int t = threadIdx.x;
  float v[8];
#pragma unroll
  for (int j = 0; j < 8; ++j) v[j] = mr[t * 8 + j];
  __shared__ float sV[256];
  __shared__ int   sI[256];
  __shared__ float topv[TOPK];
  __shared__ int   topi[TOPK];
  for (int rnd = 0; rnd < TOPK; ++rnd) {
    float bv = v[0]; int bi = t * 8;
#pragma unroll
    for (int j = 1; j < 8; ++j)
      if (v[j] > bv) { bv = v[j]; bi = t * 8 + j; }   // strict > : ties keep lowest idx
    sV[t] = bv; sI[t] = bi;
    __syncthreads();
    for (int off = 128; off > 0; off >>= 1) {
      if (t < off) {
        float ov = sV[t + off]; int oi = sI[t + off];
        if (ov > sV[t] || (ov == sV[t] && oi < sI[t])) { sV[t] = ov; sI[t] = oi; }
      }
      __syncthreads();
    }
    int wi = sI[0];
    if (t == 0) { topv[rnd] = sV[0]; topi[rnd] = wi; }
    if ((wi >> 3) == t) {
#pragma unroll
      for (int j = 0; j < 8; ++j)                    // static idx (no scratch)
        if ((wi & 7) == j) v[j] = -__builtin_inff();
    }
    __syncthreads();
  }
  if (t == 0) {
    float mx = topv[0], sum = 0.f, e[TOPK];
#pragma unroll
    for (int i = 0; i < TOPK; ++i) { e[i] = expf(topv[i] - mx); sum += e[i]; }
#pragma unroll
    for (int i = 0; i < TOPK; ++i) {
      wts[row * 8 + i]    = e[i] / sum;
      delays[row * 8 + i] = topi[i];
    }
  }
}

// ---------------- delay-roll aggregation: aggt[b][c][l] ---------------------
__global__ __launch_bounds__(256) void agg_kernel(
    const u16* __restrict__ Vt, const float* __restrict__ wts,
    const int* __restrict__ delays, u16* __restrict__ aggt)
{
  int row = blockIdx.x;           // b*1024 + c
  int c = row & 1023;             // weights index: (c>>6)*64 + (c&63) == c
  __shared__ __align__(16) float Vs[4608];
  __shared__ float wsh[TOPK];
  __shared__ int   dsh[TOPK];
  int t = threadIdx.x;
  if (t < TOPK) { wsh[t] = wts[c * 8 + t]; dsh[t] = delays[c * 8 + t]; }
  const u16* vr = Vt + (size_t)row * 2048;
  u32x4 rv = *(const u32x4*)(vr + t * 8);
  alignas(16) u16 uv[8];
  *(u32x4*)uv = rv;
  int f0 = t * 8;
#pragma unroll
  for (int j = 0; j < 8; ++j) {
    float fv = b2f(uv[j]);
    int f  = f0 + j;
    int f2 = f + 2048;
    Vs[f  + ((f  >> 5) << 2)] = fv;
    Vs[f2 + ((f2 >> 5) << 2)] = fv;
  }
  __syncthreads();
  float o[8] = {0, 0, 0, 0, 0, 0, 0, 0};
#pragma unroll
  for (int i = 0; i < TOPK; ++i) {
    float w = wsh[i]; int dl = dsh[i];
    int base = f0 + dl;
#pragma unroll
    for (int j = 0; j < 8; ++j) {
      int f = base + j;                       // <= 4094, dup covers mod L
      o[j] += w * Vs[f + ((f >> 5) << 2)];
    }
  }
  alignas(16) u16 ob[8];
#pragma unroll
  for (int j = 0; j < 8; ++j) ob[j] = f2bf(o[j]);
  *(u32x4*)(aggt + (size_t)row * 2048 + f0) = *(u32x4*)ob;
}

// ---------------- transpose aggt[b][c][l] -> aggb[b][l][c] (bf16) -----------
__global__ __launch_bounds__(256) void transpose_kernel(
    const u16* __restrict__ aggt, u16* __restrict__ aggb)
{
  int bid = blockIdx.x;
  int lt = bid & 31;
  int ct = (bid >> 5) & 15;
  int b  = bid >> 9;
  __shared__ __align__(16) u16 tile[64][72];
  int t = threadIdx.x;
  int r = t >> 2, seg = t & 3;
  const u16* src = aggt + ((size_t)(b * 1024 + ct * 64 + r)) * 2048 + lt * 64 + seg * 16;
  u32x4 v0 = *(const u32x4*)src;
  u32x4 v1 = *(const u32x4*)(src + 8);
  *(u32x4*)&tile[r][seg * 16]     = v0;
  *(u32x4*)&tile[r][seg * 16 + 8] = v1;
  __syncthreads();
  alignas(16) u16 tmp[16];
#pragma unroll
  for (int j = 0; j < 16; ++j) tmp[j] = tile[seg * 16 + j][r];
  u16* dst = aggb + ((size_t)(b * 2048 + lt * 64 + r)) * 1024 + ct * 64 + seg * 16;
  *(u32x4*)dst       = *(u32x4*)&tmp[0];
  *(u32x4*)(dst + 8) = *(u32x4*)&tmp[8];
}

// ---------------------------------------------------------------------------
extern "C" void kernel_launch(void* const* d_in, const int* in_sizes, int n_in,
                              void* d_out, int out_size, void* d_ws, size_t ws_size,
                              hipStream_t stream) {
  (void)in_sizes; (void)n_in; (void)out_size; (void)ws_size;
  const float* qin = (const float*)d_in[0];
  const float* kin = (const float*)d_in[1];
  const float* vin = (const float*)d_in[2];
  const float* Wq  = (const float*)d_in[3];
  const float* Wk  = (const float*)d_in[4];
  const float* Wv  = (const float*)d_in[5];
  const float* Wo  = (const float*)d_in[6];
  const float* bo  = (const float*)d_in[7];

  float* out  = (float*)d_out;                  // [16][2048][1024] fp32
  float* corr = out + (size_t)33554432;         // [16][1024][2048] fp32

  char* ws = (char*)d_ws;
  u16* Qt  = (u16*)ws;                                   // 64 MiB  [16][1024][2048] bf16
  u16* Kt  = (u16*)(ws + ((size_t)64  << 20));           // 64 MiB
  u16* Vt  = (u16*)(ws + ((size_t)128 << 20));           // 64 MiB
  u16* Wqb = (u16*)(ws + ((size_t)192 << 20));           // 2 MiB each
  u16* Wkb = Wqb + (1u << 20);
  u16* Wvb = Wkb + (1u << 20);
  u16* Wob = Wvb + (1u << 20);
  float* meanp  = (float*)(ws + ((size_t)200 << 20));    // 8 MiB [16][64][2048] fp32
  int*   delays = (int*)  (ws + ((size_t)208 << 20));    // [1024][8]
  float* wts    = (float*)(ws + ((size_t)208 << 20) + 65536);
  u16* aggt = Qt;   // reuse (Qt dead after corr)
  u16* aggb = Kt;   // reuse (Kt dead after corr)

  dim3 blk(256);
  cvt_kernel<<<512, blk, 0, stream>>>(Wq, Wqb, 131072);
  cvt_kernel<<<512, blk, 0, stream>>>(Wk, Wkb, 131072);
  cvt_kernel<<<512, blk, 0, stream>>>(Wv, Wvb, 131072);
  cvt_kernel<<<512, blk, 0, stream>>>(Wo, Wob, 131072);

  gemm_bt<0><<<2048, blk, 0, stream>>>(qin, Wqb, Qt, nullptr);
  gemm_bt<0><<<2048, blk, 0, stream>>>(kin, Wkb, Kt, nullptr);
  gemm_bt<0><<<2048, blk, 0, stream>>>(vin, Wvb, Vt, nullptr);

  fftcorr_kernel<<<2048, blk, 0, stream>>>(Qt, Kt, corr);
  mean_kernel<<<2048, blk, 0, stream>>>(corr, meanp);
  topk_kernel<<<1024, blk, 0, stream>>>(meanp, delays, wts);
  agg_kernel<<<16384, blk, 0, stream>>>(Vt, wts, delays, aggt);
  transpose_kernel<<<8192, blk, 0, stream>>>(aggt, aggb);
  gemm_bt<1><<<2048, blk, 0, stream>>>(aggb, Wob, out, bo);
}